// Round 9
// baseline (237.637 us; speedup 1.0000x reference)
//
#include <hip/hip_runtime.h>
#include <hip/hip_bf16.h>

#define DEVI __device__ __forceinline__

using bf16x8 = __attribute__((ext_vector_type(8))) short;
using f32x4  = __attribute__((ext_vector_type(4))) float;
using f32x16 = __attribute__((ext_vector_type(16))) float;

#define LOG2E 1.4426950408889634f

DEVI unsigned short f2bf(float f){
  unsigned int u = __float_as_uint(f);
  return (unsigned short)((u + 0x7fffu + ((u>>16)&1u)) >> 16);
}

DEVI unsigned int cvt_pk_bf16(float lo, float hi){
  unsigned int r;
  asm("v_cvt_pk_bf16_f32 %0, %1, %2" : "=v"(r) : "v"(lo), "v"(hi));
  return r;
}

#if __has_builtin(__builtin_amdgcn_exp2f)
#define EXP2(x) __builtin_amdgcn_exp2f(x)
#else
#define EXP2(x) exp2f(x)
#endif

DEVI void gload_lds16(const unsigned short* src, unsigned short* lds){
  __builtin_amdgcn_global_load_lds((const __attribute__((address_space(1))) void*)src,
                                   (__attribute__((address_space(3))) void*)lds, 16, 0, 0);
}

DEVI bf16x8 mk8(unsigned w0, unsigned w1, unsigned w2, unsigned w3){
  union { unsigned u[4]; bf16x8 v; } x;
  x.u[0]=w0; x.u[1]=w1; x.u[2]=w2; x.u[3]=w3;
  return x.v;
}

// ---------------------------------------------------------------------------
// Kernel 0: fp32 -> bf16 convert for X (y=0..2, 4M elems) and W (y=3..6, 1M).
// ---------------------------------------------------------------------------
__global__ __launch_bounds__(256) void convert_kernel(
  const float* __restrict__ Xq, const float* __restrict__ Xk, const float* __restrict__ Xv,
  const float* __restrict__ Wq, const float* __restrict__ Wk, const float* __restrict__ Wv,
  const float* __restrict__ Wo, unsigned short* __restrict__ ws)
{
  const int y = blockIdx.y;
  const float* src;
  unsigned short* dst;
  int n4;
  if (y < 3){
    src = (y==0)?Xq:((y==1)?Xk:Xv);
    dst = ws + (size_t)y*4194304;
    n4 = 1048576;
  } else {
    src = (y==3)?Wq:((y==4)?Wk:((y==5)?Wv:Wo));
    dst = ws + 12582912 + (size_t)(y-3)*1048576;
    n4 = 262144;
  }
  const int stride = gridDim.x * 256;
  for (int i = blockIdx.x*256 + threadIdx.x; i < n4; i += stride){
    float4 v = ((const float4*)src)[i];
    uint2 u;
    u.x = cvt_pk_bf16(v.x, v.y);
    u.y = cvt_pk_bf16(v.z, v.w);
    ((uint2*)dst)[i] = u;
  }
}

// ---------------------------------------------------------------------------
// Kernel 1: QKV projection GEMM.  128x128 tile, BK=32 half-steps, 3 LDS
// buffers, depth-2 prefetch with COUNTED vmcnt(4).  (validated round 6)
// ---------------------------------------------------------------------------
__global__ __launch_bounds__(256, 3) void proj_qkv_kernel(
  const unsigned short* __restrict__ Xb, const unsigned short* __restrict__ Wb,
  const float* __restrict__ Bq, const float* __restrict__ Bk, const float* __restrict__ Bv,
  unsigned short* __restrict__ Qo, unsigned short* __restrict__ Ko, unsigned short* __restrict__ Vo)
{
  const int L = blockIdx.x;
  const int xcd = L & 7, g = L >> 3;
  const int combo = xcd*12 + (g>>3);
  const int tn = g & 7;
  const int p  = combo >> 5;
  const int tm = combo & 31;

  const unsigned short* __restrict__ A = Xb + (size_t)p*4194304;
  const unsigned short* __restrict__ B = Wb + (size_t)p*1048576;
  const float* __restrict__ Bb = (p==0)?Bq:((p==1)?Bk:Bv);
  unsigned short* __restrict__ Out = (p==0)?Qo:((p==1)?Ko:Vo);
  const float oscale = (p==0)?(0.125f*LOG2E):1.0f;

  const int m0 = tm*128, n0 = tn*128;
  const int tid = threadIdx.x;
  const int w = tid>>6, l = tid&63;
  const int wr = w>>1, wc = w&1;
  const int lg = l>>4, lr = l&15;

  __shared__ unsigned short As[3][4096];
  __shared__ unsigned short Bs[3][4096];

  f32x4 acc[4][4];
  #pragma unroll
  for (int i=0;i<4;i++)
    #pragma unroll
    for (int j=0;j<4;j++){ f32x4 z = {0.f,0.f,0.f,0.f}; acc[i][j] = z; }

  const int srow = l>>2;
  const int schk = (l&3) ^ (srow&3);
  auto stage = [&](int h, int buf){
    const int kt = h*32;
    #pragma unroll
    for (int i=0;i<2;i++){
      int rbase = w*32 + i*16;
      gload_lds16(A + (size_t)(m0+rbase+srow)*1024 + kt + schk*8, &As[buf][0] + rbase*32);
      gload_lds16(B + (size_t)(n0+rbase+srow)*1024 + kt + schk*8, &Bs[buf][0] + rbase*32);
    }
  };

  stage(0, 0);
  stage(1, 1);

  const int sca = (lg ^ (lr&3)) << 4;
  int cur = 0;
  for (int h=0; h<32; ++h){
    if (h < 31) asm volatile("s_waitcnt vmcnt(4)" ::: "memory");
    else        asm volatile("s_waitcnt vmcnt(0)" ::: "memory");
    __builtin_amdgcn_s_barrier();
    __builtin_amdgcn_sched_barrier(0);
    if (h < 30){
      int nb = cur + 2; if (nb >= 3) nb -= 3;
      stage(h+2, nb);
    }

    bf16x8 af[4], bfr[4];
    #pragma unroll
    for (int f=0;f<4;f++){
      af[f]  = *(const bf16x8*)((const char*)&As[cur][0] + (wr*64 + f*16 + lr)*64 + sca);
      bfr[f] = *(const bf16x8*)((const char*)&Bs[cur][0] + (wc*64 + f*16 + lr)*64 + sca);
    }
    #pragma unroll
    for (int fr=0;fr<4;fr++)
      #pragma unroll
      for (int fc=0;fc<4;fc++)
        acc[fr][fc] = __builtin_amdgcn_mfma_f32_16x16x32_bf16(af[fr], bfr[fc], acc[fr][fc], 0,0,0);

    cur = (cur==2) ? 0 : cur+1;
  }

  if (p == 2){
    #pragma unroll
    for (int fc=0;fc<4;fc++){
      int n = n0 + wc*64 + fc*16 + lr;
      float bias = Bb[n];
      int h = n>>6, d = n&63;
      #pragma unroll
      for (int fr=0;fr<4;fr++){
        int m = m0 + wr*64 + fr*16 + lg*4;
        int b = m>>11, s = m & 2047;
        uint2 u;
        u.x = cvt_pk_bf16(acc[fr][fc][0]+bias, acc[fr][fc][1]+bias);
        u.y = cvt_pk_bf16(acc[fr][fc][2]+bias, acc[fr][fc][3]+bias);
        *(uint2*)(Out + (((size_t)((b<<4)+h)*64 + d)*2048 + s)) = u;
      }
    }
  } else {
    #pragma unroll
    for (int fc=0;fc<4;fc++){
      int n = n0 + wc*64 + fc*16 + lr;
      float bias = Bb[n];
      int h = n>>6, d = n&63;
      #pragma unroll
      for (int fr=0;fr<4;fr++){
        #pragma unroll
        for (int r=0;r<4;r++){
          int m = m0 + wr*64 + fr*16 + lg*4 + r;
          int b = m>>11, s = m & 2047;
          float v = (acc[fr][fc][r] + bias) * oscale;
          Out[ ((size_t)((b<<4)+h)*2048 + (size_t)s)*64 + d ] = f2bf(v);
        }
      }
    }
  }
}

// ---------------------------------------------------------------------------
// Kernel 2: causal flash attention, PAIRED q-tiles for perfect load balance.
// 512 blocks of 128 threads (2 waves x 32 q-rows).  Block = (pair, bh);
// processes 64-row q-tile t=31-pair then t=pair sequentially: 33 KV-steps
// every block.  XCD map: bh = 4*(idx&7)+((idx>>3)&3) -> per-XCD KV (2MB)
// stays L2-resident.  Inner step identical to validated round-3 code.
// ---------------------------------------------------------------------------
__global__ __launch_bounds__(128, 2) void attn_kernel(
  const unsigned short* __restrict__ Q, const unsigned short* __restrict__ Kg,
  const unsigned short* __restrict__ Vt, unsigned short* __restrict__ AO)
{
  const int idx = blockIdx.x;
  const int xcd = idx & 7, j = idx >> 3;
  const int bh = 4*xcd + (j & 3);
  const int pr = j >> 2;                 // pair index 0..15
  const size_t base = (size_t)bh * 131072;   // 2048*64
  const int tid = threadIdx.x, w = tid>>6, l = tid&63;
  const int lq = l & 31, hi = l >> 5;
  const int b = bh>>4, hh = bh&15;

  __shared__ unsigned short Ks[2][4096];   // [kv][d] swizzled (src-side XOR)
  __shared__ unsigned short Vs[2][4096];   // [d][kv] swizzled

  auto stage = [&](int kt, int half){
    const int kv0 = kt*64;
    #pragma unroll
    for (int i=0;i<4;i++){
      int c = tid + i*128;
      int row = c>>3;
      int kc = (c&7) ^ (row&7);
      gload_lds16(Kg + base + (size_t)(kv0+row)*64 + kc*8, &Ks[half][0] + c*8);
      gload_lds16(Vt + base + (size_t)row*2048 + kv0 + kc*8, &Vs[half][0] + c*8);
    }
  };

  #pragma unroll 1
  for (int ph=0; ph<2; ph++){
    const int t = ph ? pr : (31 - pr);   // heavy tile first
    const int q0 = t*64;
    const int qw0 = q0 + w*32;
    const int qq = qw0 + lq;

    bf16x8 qf[4];
    {
      const unsigned short* qp = Q + base + (size_t)qq*64;
      #pragma unroll
      for (int s=0;s<4;s++) qf[s] = *(const bf16x8*)(qp + s*16 + hi*8);
    }

    f32x16 oacc[2];
    #pragma unroll
    for (int dt=0;dt<2;dt++)
      #pragma unroll
      for (int r=0;r<16;r++) oacc[dt][r] = 0.f;
    float m_i = -INFINITY, l_i = 0.f;

    const int NT = t + 1;

    __syncthreads();         // guard LDS reuse across phases
    stage(0, 0);
    __syncthreads();

    for (int kt=0; kt<NT; kt++){
      const int cur = kt & 1;
      if (kt+1 < NT) stage(kt+1, cur^1);
      const int kv0 = kt*64;

      f32x16 sacc[2];
      #pragma unroll
      for (int kvt=0;kvt<2;kvt++)
        #pragma unroll
        for (int r=0;r<16;r++) sacc[kvt][r] = 0.f;

      __builtin_amdgcn_s_setprio(1);
      #pragma unroll
      for (int kvt=0;kvt<2;kvt++){
        int row = kvt*32 + lq;
        const char* kb = (const char*)&Ks[cur][0] + row*128;
        int swz = (row&7)<<4;
        #pragma unroll
        for (int s=0;s<4;s++){
          bf16x8 kf = *(const bf16x8*)(kb + ((s*32 + hi*16) ^ swz));
          sacc[kvt] = __builtin_amdgcn_mfma_f32_32x32x16_bf16(kf, qf[s], sacc[kvt], 0,0,0);
        }
      }
      __builtin_amdgcn_s_setprio(0);

      #pragma unroll
      for (int kvt=0;kvt<2;kvt++){
        if (kv0 + kvt*32 + 31 > qw0){
          #pragma unroll
          for (int r=0;r<16;r++){
            int kvv = kv0 + kvt*32 + (r&3) + 8*(r>>2) + 4*hi;
            if (kvv > qq) sacc[kvt][r] = -1e30f;
          }
        }
      }

      float mt = sacc[0][0];
      #pragma unroll
      for (int kvt=0;kvt<2;kvt++)
        #pragma unroll
        for (int r=0;r<16;r++) mt = fmaxf(mt, sacc[kvt][r]);
      mt = fmaxf(mt, __shfl_xor(mt, 32));

      if (__any(mt > m_i + 8.f)){
        float mn = fmaxf(m_i, mt);
        float sc = EXP2(m_i - mn);
        m_i = mn;
        l_i *= sc;
        #pragma unroll
        for (int dt=0;dt<2;dt++)
          #pragma unroll
          for (int r=0;r<16;r++) oacc[dt][r] *= sc;
      }
      float rs = 0.f;
      #pragma unroll
      for (int kvt=0;kvt<2;kvt++)
        #pragma unroll
        for (int r=0;r<16;r++){
          float pv = EXP2(sacc[kvt][r] - m_i);
          sacc[kvt][r] = pv;
          rs += pv;
        }
      rs += __shfl_xor(rs, 32);
      l_i += rs;

      unsigned pa[8], pb[8], sa[8], sb[8];
      #pragma unroll
      for (int g=0; g<8; g++){
        int kvt = g>>2, gl = g&3;
        pa[g] = cvt_pk_bf16(sacc[kvt][4*gl+0], sacc[kvt][4*gl+1]);
        pb[g] = cvt_pk_bf16(sacc[kvt][4*gl+2], sacc[kvt][4*gl+3]);
        sa[g] = __shfl_xor(pa[g], 32);
        sb[g] = __shfl_xor(pb[g], 32);
      }
      bf16x8 pfrag[4];
      #pragma unroll
      for (int s=0;s<4;s++){
        int g0 = (s>>1)*4 + 2*(s&1);
        unsigned w0 = hi ? sa[g0+1] : pa[g0];
        unsigned w1 = hi ? sb[g0+1] : pb[g0];
        unsigned w2 = hi ? pa[g0+1] : sa[g0];
        unsigned w3 = hi ? pb[g0+1] : sb[g0];
        pfrag[s] = mk8(w0, w1, w2, w3);
      }

      __builtin_amdgcn_s_setprio(1);
      #pragma unroll
      for (int dt=0;dt<2;dt++){
        int row = dt*32 + lq;
        const char* vb = (const char*)&Vs[cur][0] + row*128;
        int swz = (row&7)<<4;
        #pragma unroll
        for (int s=0;s<4;s++){
          bf16x8 vf = *(const bf16x8*)(vb + ((s*32 + hi*16) ^ swz));
          oacc[dt] = __builtin_amdgcn_mfma_f32_32x32x16_bf16(vf, pfrag[s], oacc[dt], 0,0,0);
        }
      }
      __builtin_amdgcn_s_setprio(0);

      __syncthreads();
    }

    // epilogue: O^T -> LDS transpose (wave-private half of Ks[0]) -> stores
    unsigned short* Es = &Ks[0][0] + w*2048;
    float inv = 1.0f / l_i;
    {
      char* eb = (char*)Es + lq*128;
      int swz = (lq&7)<<4;
      #pragma unroll
      for (int dt=0;dt<2;dt++)
        #pragma unroll
        for (int g=0;g<4;g++){
          int d0 = dt*32 + 8*g + 4*hi;
          unsigned u0 = cvt_pk_bf16(oacc[dt][4*g+0]*inv, oacc[dt][4*g+1]*inv);
          unsigned u1 = cvt_pk_bf16(oacc[dt][4*g+2]*inv, oacc[dt][4*g+3]*inv);
          *(unsigned*)(eb + ((d0*2    ) ^ swz)) = u0;
          *(unsigned*)(eb + ((d0*2 + 4) ^ swz)) = u1;
        }
    }
    {
      const char* rb = (const char*)Es + lq*128;
      int swz = (lq&7)<<4;
      unsigned short* op = AO + ((size_t)b*2048 + qq)*1024 + hh*64 + hi*32;
      #pragma unroll
      for (int jj=0;jj<4;jj++){
        bf16x8 v = *(const bf16x8*)(rb + ((hi*64 + jj*16) ^ swz));
        *(bf16x8*)(op + jj*8) = v;
      }
    }
  }
}

// ---------------------------------------------------------------------------
// Kernel 3: output projection — depth-2 counted-vmcnt structure (validated).
// ---------------------------------------------------------------------------
__global__ __launch_bounds__(256, 3) void proj_out_kernel(
  const unsigned short* __restrict__ A, const unsigned short* __restrict__ B,
  const float* __restrict__ Bb, float* __restrict__ Out)
{
  const int L = blockIdx.x;
  const int xcd = L & 7, g = L >> 3;
  const int tm = xcd*4 + (g>>3);
  const int tn = g & 7;
  const int m0 = tm*128, n0 = tn*128;
  const int tid = threadIdx.x;
  const int w = tid>>6, l = tid&63;
  const int wr = w>>1, wc = w&1;
  const int lg = l>>4, lr = l&15;

  __shared__ unsigned short As[3][4096];
  __shared__ unsigned short Bs[3][4096];

  f32x4 acc[4][4];
  #pragma unroll
  for (int i=0;i<4;i++)
    #pragma unroll
    for (int j=0;j<4;j++){ f32x4 z = {0.f,0.f,0.f,0.f}; acc[i][j] = z; }

  const int srow = l>>2;
  const int schk = (l&3) ^ (srow&3);
  auto stage = [&](int h, int buf){
    const int kt = h*32;
    #pragma unroll
    for (int i=0;i<2;i++){
      int rbase = w*32 + i*16;
      gload_lds16(A + (size_t)(m0+rbase+srow)*1024 + kt + schk*8, &As[buf][0] + rbase*32);
      gload_lds16(B + (size_t)(n0+rbase+srow)*1024 + kt + schk*8, &Bs[buf][0] + rbase*32);
    }
  };

  stage(0, 0);
  stage(1, 1);

  const int sca = (lg ^ (lr&3)) << 4;
  int cur = 0;
  for (int h=0; h<32; ++h){
    if (h < 31) asm volatile("s_waitcnt vmcnt(4)" ::: "memory");
    else        asm volatile("s_waitcnt vmcnt(0)" ::: "memory");
    __builtin_amdgcn_s_barrier();
    __builtin_amdgcn_sched_barrier(0);
    if (h < 30){
      int nb = cur + 2; if (nb >= 3) nb -= 3;
      stage(h+2, nb);
    }

    bf16x8 af[4], bfr[4];
    #pragma unroll
    for (int f=0;f<4;f++){
      af[f]  = *(const bf16x8*)((const char*)&As[cur][0] + (wr*64 + f*16 + lr)*64 + sca);
      bfr[f] = *(const bf16x8*)((const char*)&Bs[cur][0] + (wc*64 + f*16 + lr)*64 + sca);
    }
    #pragma unroll
    for (int fr=0;fr<4;fr++)
      #pragma unroll
      for (int fc=0;fc<4;fc++)
        acc[fr][fc] = __builtin_amdgcn_mfma_f32_16x16x32_bf16(af[fr], bfr[fc], acc[fr][fc], 0,0,0);

    cur = (cur==2) ? 0 : cur+1;
  }

  #pragma unroll
  for (int fc=0;fc<4;fc++){
    int n = n0 + wc*64 + fc*16 + lr;
    float bias = Bb[n];
    #pragma unroll
    for (int fr=0;fr<4;fr++){
      #pragma unroll
      for (int r=0;r<4;r++){
        int m = m0 + wr*64 + fr*16 + lg*4 + r;
        Out[(size_t)m*1024 + n] = acc[fr][fc][r] + bias;
      }
    }
  }
}

// ---------------------------------------------------------------------------
extern "C" void kernel_launch(void* const* d_in, const int* in_sizes, int n_in,
                              void* d_out, int out_size, void* d_ws, size_t ws_size,
                              hipStream_t stream)
{
  const float* Xq = (const float*)d_in[0];
  const float* Xk = (const float*)d_in[1];
  const float* Xv = (const float*)d_in[2];
  // d_in[3] = mask (causal, static) — unused
  const float* Wq = (const float*)d_in[4];
  const float* bq = (const float*)d_in[5];
  const float* Wk = (const float*)d_in[6];
  const float* bk = (const float*)d_in[7];
  const float* Wv = (const float*)d_in[8];
  const float* bv = (const float*)d_in[9];
  const float* Wo = (const float*)d_in[10];
  const float* bo = (const float*)d_in[11];

  unsigned short* ws  = (unsigned short*)d_ws;
  unsigned short* Xb  = ws;
  unsigned short* Wb  = ws + 12582912;
  unsigned short* Qw  = ws + 16777216;
  unsigned short* Kw  = ws + 20971520;
  unsigned short* Vw  = ws + 25165824;
  unsigned short* AOw = ws + 29360128;
  float* out = (float*)d_out;

  convert_kernel<<<dim3(512,7), 256, 0, stream>>>(Xq,Xk,Xv,Wq,Wk,Wv,Wo, ws);
  proj_qkv_kernel<<<768, 256, 0, stream>>>(Xb, Wb, bq,bk,bv, Qw,Kw,Vw);
  attn_kernel<<<512, 128, 0, stream>>>(Qw,Kw,Vw,AOw);
  proj_out_kernel<<<256, 256, 0, stream>>>(AOw, Wb + 3*1048576, bo, out);
}

// Round 10
// 221.820 us; speedup vs baseline: 1.0713x; 1.0713x over previous
//
#include <hip/hip_runtime.h>
#include <hip/hip_bf16.h>

#define DEVI __device__ __forceinline__

using bf16x8 = __attribute__((ext_vector_type(8))) short;
using f32x4  = __attribute__((ext_vector_type(4))) float;
using f32x16 = __attribute__((ext_vector_type(16))) float;

#define LOG2E 1.4426950408889634f

DEVI unsigned short f2bf(float f){
  unsigned int u = __float_as_uint(f);
  return (unsigned short)((u + 0x7fffu + ((u>>16)&1u)) >> 16);
}

DEVI unsigned int cvt_pk_bf16(float lo, float hi){
  unsigned int r;
  asm("v_cvt_pk_bf16_f32 %0, %1, %2" : "=v"(r) : "v"(lo), "v"(hi));
  return r;
}

#if __has_builtin(__builtin_amdgcn_exp2f)
#define EXP2(x) __builtin_amdgcn_exp2f(x)
#else
#define EXP2(x) exp2f(x)
#endif

DEVI void gload_lds16(const unsigned short* src, unsigned short* lds){
  __builtin_amdgcn_global_load_lds((const __attribute__((address_space(1))) void*)src,
                                   (__attribute__((address_space(3))) void*)lds, 16, 0, 0);
}

DEVI bf16x8 mk8(unsigned w0, unsigned w1, unsigned w2, unsigned w3){
  union { unsigned u[4]; bf16x8 v; } x;
  x.u[0]=w0; x.u[1]=w1; x.u[2]=w2; x.u[3]=w3;
  return x.v;
}

// ---------------------------------------------------------------------------
// Kernel 0: fp32 -> bf16 convert for X (y=0..2, 4M elems) and W (y=3..6, 1M).
// ---------------------------------------------------------------------------
__global__ __launch_bounds__(256) void convert_kernel(
  const float* __restrict__ Xq, const float* __restrict__ Xk, const float* __restrict__ Xv,
  const float* __restrict__ Wq, const float* __restrict__ Wk, const float* __restrict__ Wv,
  const float* __restrict__ Wo, unsigned short* __restrict__ ws)
{
  const int y = blockIdx.y;
  const float* src;
  unsigned short* dst;
  int n4;
  if (y < 3){
    src = (y==0)?Xq:((y==1)?Xk:Xv);
    dst = ws + (size_t)y*4194304;
    n4 = 1048576;
  } else {
    src = (y==3)?Wq:((y==4)?Wk:((y==5)?Wv:Wo));
    dst = ws + 12582912 + (size_t)(y-3)*1048576;
    n4 = 262144;
  }
  const int stride = gridDim.x * 256;
  for (int i = blockIdx.x*256 + threadIdx.x; i < n4; i += stride){
    float4 v = ((const float4*)src)[i];
    uint2 u;
    u.x = cvt_pk_bf16(v.x, v.y);
    u.y = cvt_pk_bf16(v.z, v.w);
    ((uint2*)dst)[i] = u;
  }
}

// ---------------------------------------------------------------------------
// Kernel 1: QKV projection GEMM.  128x128 tile, BK=32 half-steps, 3 LDS
// buffers, depth-2 prefetch with COUNTED vmcnt(4).  (validated round 6)
// ---------------------------------------------------------------------------
__global__ __launch_bounds__(256, 3) void proj_qkv_kernel(
  const unsigned short* __restrict__ Xb, const unsigned short* __restrict__ Wb,
  const float* __restrict__ Bq, const float* __restrict__ Bk, const float* __restrict__ Bv,
  unsigned short* __restrict__ Qo, unsigned short* __restrict__ Ko, unsigned short* __restrict__ Vo)
{
  const int L = blockIdx.x;
  const int xcd = L & 7, g = L >> 3;
  const int combo = xcd*12 + (g>>3);
  const int tn = g & 7;
  const int p  = combo >> 5;
  const int tm = combo & 31;

  const unsigned short* __restrict__ A = Xb + (size_t)p*4194304;
  const unsigned short* __restrict__ B = Wb + (size_t)p*1048576;
  const float* __restrict__ Bb = (p==0)?Bq:((p==1)?Bk:Bv);
  unsigned short* __restrict__ Out = (p==0)?Qo:((p==1)?Ko:Vo);
  const float oscale = (p==0)?(0.125f*LOG2E):1.0f;

  const int m0 = tm*128, n0 = tn*128;
  const int tid = threadIdx.x;
  const int w = tid>>6, l = tid&63;
  const int wr = w>>1, wc = w&1;
  const int lg = l>>4, lr = l&15;

  __shared__ unsigned short As[3][4096];
  __shared__ unsigned short Bs[3][4096];

  f32x4 acc[4][4];
  #pragma unroll
  for (int i=0;i<4;i++)
    #pragma unroll
    for (int j=0;j<4;j++){ f32x4 z = {0.f,0.f,0.f,0.f}; acc[i][j] = z; }

  const int srow = l>>2;
  const int schk = (l&3) ^ (srow&3);
  auto stage = [&](int h, int buf){
    const int kt = h*32;
    #pragma unroll
    for (int i=0;i<2;i++){
      int rbase = w*32 + i*16;
      gload_lds16(A + (size_t)(m0+rbase+srow)*1024 + kt + schk*8, &As[buf][0] + rbase*32);
      gload_lds16(B + (size_t)(n0+rbase+srow)*1024 + kt + schk*8, &Bs[buf][0] + rbase*32);
    }
  };

  stage(0, 0);
  stage(1, 1);

  const int sca = (lg ^ (lr&3)) << 4;
  int cur = 0;
  for (int h=0; h<32; ++h){
    if (h < 31) asm volatile("s_waitcnt vmcnt(4)" ::: "memory");
    else        asm volatile("s_waitcnt vmcnt(0)" ::: "memory");
    __builtin_amdgcn_s_barrier();
    __builtin_amdgcn_sched_barrier(0);
    if (h < 30){
      int nb = cur + 2; if (nb >= 3) nb -= 3;
      stage(h+2, nb);
    }

    bf16x8 af[4], bfr[4];
    #pragma unroll
    for (int f=0;f<4;f++){
      af[f]  = *(const bf16x8*)((const char*)&As[cur][0] + (wr*64 + f*16 + lr)*64 + sca);
      bfr[f] = *(const bf16x8*)((const char*)&Bs[cur][0] + (wc*64 + f*16 + lr)*64 + sca);
    }
    #pragma unroll
    for (int fr=0;fr<4;fr++)
      #pragma unroll
      for (int fc=0;fc<4;fc++)
        acc[fr][fc] = __builtin_amdgcn_mfma_f32_16x16x32_bf16(af[fr], bfr[fc], acc[fr][fc], 0,0,0);

    cur = (cur==2) ? 0 : cur+1;
  }

  if (p == 2){
    #pragma unroll
    for (int fc=0;fc<4;fc++){
      int n = n0 + wc*64 + fc*16 + lr;
      float bias = Bb[n];
      int h = n>>6, d = n&63;
      #pragma unroll
      for (int fr=0;fr<4;fr++){
        int m = m0 + wr*64 + fr*16 + lg*4;
        int b = m>>11, s = m & 2047;
        uint2 u;
        u.x = cvt_pk_bf16(acc[fr][fc][0]+bias, acc[fr][fc][1]+bias);
        u.y = cvt_pk_bf16(acc[fr][fc][2]+bias, acc[fr][fc][3]+bias);
        *(uint2*)(Out + (((size_t)((b<<4)+h)*64 + d)*2048 + s)) = u;
      }
    }
  } else {
    #pragma unroll
    for (int fc=0;fc<4;fc++){
      int n = n0 + wc*64 + fc*16 + lr;
      float bias = Bb[n];
      int h = n>>6, d = n&63;
      #pragma unroll
      for (int fr=0;fr<4;fr++){
        #pragma unroll
        for (int r=0;r<4;r++){
          int m = m0 + wr*64 + fr*16 + lg*4 + r;
          int b = m>>11, s = m & 2047;
          float v = (acc[fr][fc][r] + bias) * oscale;
          Out[ ((size_t)((b<<4)+h)*2048 + (size_t)s)*64 + d ] = f2bf(v);
        }
      }
    }
  }
}

// ---------------------------------------------------------------------------
// Kernel 2: causal flash attention — paired q-tiles AND 2 waves/SIMD.
// 512 blocks x 256 thr (4 waves).  Wave = (qhalf = w>>1, par = w&1).
// Block (pair pr, bh): tile hi=31-pr then lo=pr; per tile, macro-steps of
// 128 kv (two 64-tiles); parity-0 wave computes even tile, parity-1 odd.
// M_hi + M_lo = 17 for every pr -> perfectly balanced, 2048 waves = 2/SIMD.
// End-of-phase split-softmax merge (par1 -> par0) via LDS, folded into
// the epilogue.  XCD map keeps each bh's KV L2-resident.
// ---------------------------------------------------------------------------
__global__ __launch_bounds__(256, 2) void attn_kernel(
  const unsigned short* __restrict__ Q, const unsigned short* __restrict__ Kg,
  const unsigned short* __restrict__ Vt, unsigned short* __restrict__ AO)
{
  const int idx = blockIdx.x;
  const int xcd = idx & 7, j0 = idx >> 3;
  const int bh = 4*xcd + (j0 & 3);
  const int pr = j0 >> 2;                 // pair index 0..15
  const size_t base = (size_t)bh * 131072; // 2048*64
  const int tid = threadIdx.x, w = tid>>6, l = tid&63;
  const int lq = l & 31, hi = l >> 5;
  const int qhalf = w >> 1, par = w & 1;
  const int b = bh>>4, hh = bh&15;

  __shared__ unsigned short Ks[2][8192];   // [128 kv][64 d], row-swizzled
  __shared__ unsigned short Vs[2][8192];   // [64 d][128 kv], row-swizzled

  // stage one 128-kv macro-tile (K rows 128x64, V^T rows 64x128)
  auto stage = [&](int mj, int half){
    const int kv0 = mj*128;
    #pragma unroll
    for (int i=0;i<4;i++){
      int c = tid + i*256;
      int krow = c>>3;
      int kc = (c&7) ^ (krow&7);
      gload_lds16(Kg + base + (size_t)(kv0+krow)*64 + kc*8, &Ks[half][0] + c*8);
      int vrow = c>>4;
      int vc = (c&15) ^ (vrow&15);
      gload_lds16(Vt + base + (size_t)vrow*2048 + kv0 + vc*8, &Vs[half][0] + c*8);
    }
  };

  #pragma unroll 1
  for (int ph=0; ph<2; ph++){
    const int t = ph ? pr : (31 - pr);    // heavy tile first
    const int q0 = t*64;
    const int qw0 = q0 + qhalf*32;
    const int qq = qw0 + lq;
    const int NT = t + 1;                 // 64-kv tiles
    const int M = (NT+1) >> 1;            // 128-kv macro-steps

    bf16x8 qf[4];
    {
      const unsigned short* qp = Q + base + (size_t)qq*64;
      #pragma unroll
      for (int s=0;s<4;s++) qf[s] = *(const bf16x8*)(qp + s*16 + hi*8);
    }

    f32x16 oacc[2];
    #pragma unroll
    for (int dt=0;dt<2;dt++)
      #pragma unroll
      for (int r=0;r<16;r++) oacc[dt][r] = 0.f;
    float m_i = -INFINITY, l_i = 0.f;

    __syncthreads();          // guard LDS reuse (prev phase epilogue/merge)
    stage(0, 0);
    __syncthreads();

    for (int mj=0; mj<M; mj++){
      const int cur = mj & 1;
      if (mj+1 < M) stage(mj+1, cur^1);
      const int kt = 2*mj + par;
      if (kt < NT){
        const int kv0 = kt*64;
        const int rbase = par*64;       // this wave's 64-kv half in LDS

        f32x16 sacc[2];
        #pragma unroll
        for (int kvt=0;kvt<2;kvt++)
          #pragma unroll
          for (int r=0;r<16;r++) sacc[kvt][r] = 0.f;

        __builtin_amdgcn_s_setprio(1);
        #pragma unroll
        for (int kvt=0;kvt<2;kvt++){
          int row = rbase + kvt*32 + lq;
          const char* kb = (const char*)&Ks[cur][0] + row*128;
          int swz = (row&7)<<4;
          #pragma unroll
          for (int s=0;s<4;s++){
            bf16x8 kf = *(const bf16x8*)(kb + ((s*32 + hi*16) ^ swz));
            sacc[kvt] = __builtin_amdgcn_mfma_f32_32x32x16_bf16(kf, qf[s], sacc[kvt], 0,0,0);
          }
        }
        __builtin_amdgcn_s_setprio(0);

        #pragma unroll
        for (int kvt=0;kvt<2;kvt++){
          if (kv0 + kvt*32 + 31 > qw0){
            #pragma unroll
            for (int r=0;r<16;r++){
              int kvv = kv0 + kvt*32 + (r&3) + 8*(r>>2) + 4*hi;
              if (kvv > qq) sacc[kvt][r] = -1e30f;
            }
          }
        }

        float mt = sacc[0][0];
        #pragma unroll
        for (int kvt=0;kvt<2;kvt++)
          #pragma unroll
          for (int r=0;r<16;r++) mt = fmaxf(mt, sacc[kvt][r]);
        mt = fmaxf(mt, __shfl_xor(mt, 32));

        if (__any(mt > m_i + 8.f)){
          float mn = fmaxf(m_i, mt);
          float sc = EXP2(m_i - mn);
          m_i = mn;
          l_i *= sc;
          #pragma unroll
          for (int dt=0;dt<2;dt++)
            #pragma unroll
            for (int r=0;r<16;r++) oacc[dt][r] *= sc;
        }
        float rs = 0.f;
        #pragma unroll
        for (int kvt=0;kvt<2;kvt++)
          #pragma unroll
          for (int r=0;r<16;r++){
            float pv = EXP2(sacc[kvt][r] - m_i);
            sacc[kvt][r] = pv;
            rs += pv;
          }
        rs += __shfl_xor(rs, 32);
        l_i += rs;

        unsigned pa[8], pb[8], sa[8], sb[8];
        #pragma unroll
        for (int g=0; g<8; g++){
          int kvt = g>>2, gl = g&3;
          pa[g] = cvt_pk_bf16(sacc[kvt][4*gl+0], sacc[kvt][4*gl+1]);
          pb[g] = cvt_pk_bf16(sacc[kvt][4*gl+2], sacc[kvt][4*gl+3]);
          sa[g] = __shfl_xor(pa[g], 32);
          sb[g] = __shfl_xor(pb[g], 32);
        }
        bf16x8 pfrag[4];
        #pragma unroll
        for (int s=0;s<4;s++){
          int g0 = (s>>1)*4 + 2*(s&1);
          unsigned w0 = hi ? sa[g0+1] : pa[g0];
          unsigned w1 = hi ? sb[g0+1] : pb[g0];
          unsigned w2 = hi ? pa[g0+1] : sa[g0];
          unsigned w3 = hi ? pb[g0+1] : sb[g0];
          pfrag[s] = mk8(w0, w1, w2, w3);
        }

        __builtin_amdgcn_s_setprio(1);
        #pragma unroll
        for (int dt=0;dt<2;dt++){
          int d = dt*32 + lq;
          const char* vb = (const char*)&Vs[cur][0] + d*256;
          int swz = (d&15)<<4;
          #pragma unroll
          for (int s=0;s<4;s++){
            bf16x8 vf = *(const bf16x8*)(vb + ((par*128 + s*32 + hi*16) ^ swz));
            oacc[dt] = __builtin_amdgcn_mfma_f32_32x32x16_bf16(vf, pfrag[s], oacc[dt], 0,0,0);
          }
        }
        __builtin_amdgcn_s_setprio(0);
      }
      __syncthreads();
    }

    // ---- split-softmax merge: par1 partials -> LDS -> par0 combines
    float* mb = (float*)&Ks[0][0] + qhalf*2176;   // 34 regs x 64 lanes
    if (par == 1){
      #pragma unroll
      for (int dt=0;dt<2;dt++)
        #pragma unroll
        for (int r=0;r<16;r++) mb[(dt*16+r)*64 + l] = oacc[dt][r];
      mb[32*64 + l] = m_i;
      mb[33*64 + l] = l_i;
    }
    __syncthreads();
    if (par == 0){
      float m1  = mb[32*64 + l];
      float l1v = mb[33*64 + l];
      float mn = fmaxf(m_i, m1);
      float s0 = EXP2(m_i - mn);
      float s1 = EXP2(m1 - mn);
      float inv = 1.0f / (l_i*s0 + l1v*s1);
      float f0 = s0*inv, f1 = s1*inv;

      unsigned short* Es = &Vs[0][0] + qhalf*2048;
      char* eb = (char*)Es + lq*128;
      int swz = (lq&7)<<4;
      #pragma unroll
      for (int dt=0;dt<2;dt++)
        #pragma unroll
        for (int g=0;g<4;g++){
          int d0 = dt*32 + 8*g + 4*hi;
          float v0 = oacc[dt][4*g+0]*f0 + mb[(dt*16+4*g+0)*64+l]*f1;
          float v1 = oacc[dt][4*g+1]*f0 + mb[(dt*16+4*g+1)*64+l]*f1;
          float v2 = oacc[dt][4*g+2]*f0 + mb[(dt*16+4*g+2)*64+l]*f1;
          float v3 = oacc[dt][4*g+3]*f0 + mb[(dt*16+4*g+3)*64+l]*f1;
          *(unsigned*)(eb + ((d0*2    ) ^ swz)) = cvt_pk_bf16(v0, v1);
          *(unsigned*)(eb + ((d0*2 + 4) ^ swz)) = cvt_pk_bf16(v2, v3);
        }
      // same-wave readback -> coalesced stores
      const char* rb = (const char*)Es + lq*128;
      unsigned short* op = AO + ((size_t)b*2048 + qq)*1024 + hh*64 + hi*32;
      #pragma unroll
      for (int jj=0;jj<4;jj++){
        bf16x8 v = *(const bf16x8*)(rb + ((hi*64 + jj*16) ^ swz));
        *(bf16x8*)(op + jj*8) = v;
      }
    }
  }
}

// ---------------------------------------------------------------------------
// Kernel 3: output projection — depth-2 counted-vmcnt structure (validated).
// ---------------------------------------------------------------------------
__global__ __launch_bounds__(256, 3) void proj_out_kernel(
  const unsigned short* __restrict__ A, const unsigned short* __restrict__ B,
  const float* __restrict__ Bb, float* __restrict__ Out)
{
  const int L = blockIdx.x;
  const int xcd = L & 7, g = L >> 3;
  const int tm = xcd*4 + (g>>3);
  const int tn = g & 7;
  const int m0 = tm*128, n0 = tn*128;
  const int tid = threadIdx.x;
  const int w = tid>>6, l = tid&63;
  const int wr = w>>1, wc = w&1;
  const int lg = l>>4, lr = l&15;

  __shared__ unsigned short As[3][4096];
  __shared__ unsigned short Bs[3][4096];

  f32x4 acc[4][4];
  #pragma unroll
  for (int i=0;i<4;i++)
    #pragma unroll
    for (int j=0;j<4;j++){ f32x4 z = {0.f,0.f,0.f,0.f}; acc[i][j] = z; }

  const int srow = l>>2;
  const int schk = (l&3) ^ (srow&3);
  auto stage = [&](int h, int buf){
    const int kt = h*32;
    #pragma unroll
    for (int i=0;i<2;i++){
      int rbase = w*32 + i*16;
      gload_lds16(A + (size_t)(m0+rbase+srow)*1024 + kt + schk*8, &As[buf][0] + rbase*32);
      gload_lds16(B + (size_t)(n0+rbase+srow)*1024 + kt + schk*8, &Bs[buf][0] + rbase*32);
    }
  };

  stage(0, 0);
  stage(1, 1);

  const int sca = (lg ^ (lr&3)) << 4;
  int cur = 0;
  for (int h=0; h<32; ++h){
    if (h < 31) asm volatile("s_waitcnt vmcnt(4)" ::: "memory");
    else        asm volatile("s_waitcnt vmcnt(0)" ::: "memory");
    __builtin_amdgcn_s_barrier();
    __builtin_amdgcn_sched_barrier(0);
    if (h < 30){
      int nb = cur + 2; if (nb >= 3) nb -= 3;
      stage(h+2, nb);
    }

    bf16x8 af[4], bfr[4];
    #pragma unroll
    for (int f=0;f<4;f++){
      af[f]  = *(const bf16x8*)((const char*)&As[cur][0] + (wr*64 + f*16 + lr)*64 + sca);
      bfr[f] = *(const bf16x8*)((const char*)&Bs[cur][0] + (wc*64 + f*16 + lr)*64 + sca);
    }
    #pragma unroll
    for (int fr=0;fr<4;fr++)
      #pragma unroll
      for (int fc=0;fc<4;fc++)
        acc[fr][fc] = __builtin_amdgcn_mfma_f32_16x16x32_bf16(af[fr], bfr[fc], acc[fr][fc], 0,0,0);

    cur = (cur==2) ? 0 : cur+1;
  }

  #pragma unroll
  for (int fc=0;fc<4;fc++){
    int n = n0 + wc*64 + fc*16 + lr;
    float bias = Bb[n];
    #pragma unroll
    for (int fr=0;fr<4;fr++){
      #pragma unroll
      for (int r=0;r<4;r++){
        int m = m0 + wr*64 + fr*16 + lg*4 + r;
        Out[(size_t)m*1024 + n] = acc[fr][fc][r] + bias;
      }
    }
  }
}

// ---------------------------------------------------------------------------
extern "C" void kernel_launch(void* const* d_in, const int* in_sizes, int n_in,
                              void* d_out, int out_size, void* d_ws, size_t ws_size,
                              hipStream_t stream)
{
  const float* Xq = (const float*)d_in[0];
  const float* Xk = (const float*)d_in[1];
  const float* Xv = (const float*)d_in[2];
  // d_in[3] = mask (causal, static) — unused
  const float* Wq = (const float*)d_in[4];
  const float* bq = (const float*)d_in[5];
  const float* Wk = (const float*)d_in[6];
  const float* bk = (const float*)d_in[7];
  const float* Wv = (const float*)d_in[8];
  const float* bv = (const float*)d_in[9];
  const float* Wo = (const float*)d_in[10];
  const float* bo = (const float*)d_in[11];

  unsigned short* ws  = (unsigned short*)d_ws;
  unsigned short* Xb  = ws;
  unsigned short* Wb  = ws + 12582912;
  unsigned short* Qw  = ws + 16777216;
  unsigned short* Kw  = ws + 20971520;
  unsigned short* Vw  = ws + 25165824;
  unsigned short* AOw = ws + 29360128;
  float* out = (float*)d_out;

  convert_kernel<<<dim3(512,7), 256, 0, stream>>>(Xq,Xk,Xv,Wq,Wk,Wv,Wo, ws);
  proj_qkv_kernel<<<768, 256, 0, stream>>>(Xb, Wb, bq,bk,bv, Qw,Kw,Vw);
  attn_kernel<<<512, 256, 0, stream>>>(Qw,Kw,Vw,AOw);
  proj_out_kernel<<<256, 256, 0, stream>>>(AOw, Wb + 3*1048576, bo, out);
}

// Round 11
// 217.710 us; speedup vs baseline: 1.0915x; 1.0189x over previous
//
#include <hip/hip_runtime.h>
#include <hip/hip_bf16.h>

#define DEVI __device__ __forceinline__

using bf16x8 = __attribute__((ext_vector_type(8))) short;
using f32x4  = __attribute__((ext_vector_type(4))) float;
using f32x16 = __attribute__((ext_vector_type(16))) float;

#define LOG2E 1.4426950408889634f

DEVI unsigned short f2bf(float f){
  unsigned int u = __float_as_uint(f);
  return (unsigned short)((u + 0x7fffu + ((u>>16)&1u)) >> 16);
}

DEVI unsigned int cvt_pk_bf16(float lo, float hi){
  unsigned int r;
  asm("v_cvt_pk_bf16_f32 %0, %1, %2" : "=v"(r) : "v"(lo), "v"(hi));
  return r;
}

#if __has_builtin(__builtin_amdgcn_exp2f)
#define EXP2(x) __builtin_amdgcn_exp2f(x)
#else
#define EXP2(x) exp2f(x)
#endif

DEVI void gload_lds16(const unsigned short* src, unsigned short* lds){
  __builtin_amdgcn_global_load_lds((const __attribute__((address_space(1))) void*)src,
                                   (__attribute__((address_space(3))) void*)lds, 16, 0, 0);
}

DEVI bf16x8 mk8(unsigned w0, unsigned w1, unsigned w2, unsigned w3){
  union { unsigned u[4]; bf16x8 v; } x;
  x.u[0]=w0; x.u[1]=w1; x.u[2]=w2; x.u[3]=w3;
  return x.v;
}

// ---------------------------------------------------------------------------
// Kernel 0: fp32 -> bf16 convert for X (y=0..2, 4M elems) and W (y=3..6, 1M).
// ---------------------------------------------------------------------------
__global__ __launch_bounds__(256) void convert_kernel(
  const float* __restrict__ Xq, const float* __restrict__ Xk, const float* __restrict__ Xv,
  const float* __restrict__ Wq, const float* __restrict__ Wk, const float* __restrict__ Wv,
  const float* __restrict__ Wo, unsigned short* __restrict__ ws)
{
  const int y = blockIdx.y;
  const float* src;
  unsigned short* dst;
  int n4;
  if (y < 3){
    src = (y==0)?Xq:((y==1)?Xk:Xv);
    dst = ws + (size_t)y*4194304;
    n4 = 1048576;
  } else {
    src = (y==3)?Wq:((y==4)?Wk:((y==5)?Wv:Wo));
    dst = ws + 12582912 + (size_t)(y-3)*1048576;
    n4 = 262144;
  }
  const int stride = gridDim.x * 256;
  for (int i = blockIdx.x*256 + threadIdx.x; i < n4; i += stride){
    float4 v = ((const float4*)src)[i];
    uint2 u;
    u.x = cvt_pk_bf16(v.x, v.y);
    u.y = cvt_pk_bf16(v.z, v.w);
    ((uint2*)dst)[i] = u;
  }
}

// ---------------------------------------------------------------------------
// Kernel 1: QKV projection GEMM.  128x128 tile, BK=32 half-steps, 3 LDS
// buffers, depth-2 prefetch with COUNTED vmcnt(4).  (validated round 6)
// ---------------------------------------------------------------------------
__global__ __launch_bounds__(256, 3) void proj_qkv_kernel(
  const unsigned short* __restrict__ Xb, const unsigned short* __restrict__ Wb,
  const float* __restrict__ Bq, const float* __restrict__ Bk, const float* __restrict__ Bv,
  unsigned short* __restrict__ Qo, unsigned short* __restrict__ Ko, unsigned short* __restrict__ Vo)
{
  const int L = blockIdx.x;
  const int xcd = L & 7, g = L >> 3;
  const int combo = xcd*12 + (g>>3);
  const int tn = g & 7;
  const int p  = combo >> 5;
  const int tm = combo & 31;

  const unsigned short* __restrict__ A = Xb + (size_t)p*4194304;
  const unsigned short* __restrict__ B = Wb + (size_t)p*1048576;
  const float* __restrict__ Bb = (p==0)?Bq:((p==1)?Bk:Bv);
  unsigned short* __restrict__ Out = (p==0)?Qo:((p==1)?Ko:Vo);
  const float oscale = (p==0)?(0.125f*LOG2E):1.0f;

  const int m0 = tm*128, n0 = tn*128;
  const int tid = threadIdx.x;
  const int w = tid>>6, l = tid&63;
  const int wr = w>>1, wc = w&1;
  const int lg = l>>4, lr = l&15;

  __shared__ unsigned short As[3][4096];
  __shared__ unsigned short Bs[3][4096];

  f32x4 acc[4][4];
  #pragma unroll
  for (int i=0;i<4;i++)
    #pragma unroll
    for (int j=0;j<4;j++){ f32x4 z = {0.f,0.f,0.f,0.f}; acc[i][j] = z; }

  const int srow = l>>2;
  const int schk = (l&3) ^ (srow&3);
  auto stage = [&](int h, int buf){
    const int kt = h*32;
    #pragma unroll
    for (int i=0;i<2;i++){
      int rbase = w*32 + i*16;
      gload_lds16(A + (size_t)(m0+rbase+srow)*1024 + kt + schk*8, &As[buf][0] + rbase*32);
      gload_lds16(B + (size_t)(n0+rbase+srow)*1024 + kt + schk*8, &Bs[buf][0] + rbase*32);
    }
  };

  stage(0, 0);
  stage(1, 1);

  const int sca = (lg ^ (lr&3)) << 4;
  int cur = 0;
  for (int h=0; h<32; ++h){
    if (h < 31) asm volatile("s_waitcnt vmcnt(4)" ::: "memory");
    else        asm volatile("s_waitcnt vmcnt(0)" ::: "memory");
    __builtin_amdgcn_s_barrier();
    __builtin_amdgcn_sched_barrier(0);
    if (h < 30){
      int nb = cur + 2; if (nb >= 3) nb -= 3;
      stage(h+2, nb);
    }

    bf16x8 af[4], bfr[4];
    #pragma unroll
    for (int f=0;f<4;f++){
      af[f]  = *(const bf16x8*)((const char*)&As[cur][0] + (wr*64 + f*16 + lr)*64 + sca);
      bfr[f] = *(const bf16x8*)((const char*)&Bs[cur][0] + (wc*64 + f*16 + lr)*64 + sca);
    }
    #pragma unroll
    for (int fr=0;fr<4;fr++)
      #pragma unroll
      for (int fc=0;fc<4;fc++)
        acc[fr][fc] = __builtin_amdgcn_mfma_f32_16x16x32_bf16(af[fr], bfr[fc], acc[fr][fc], 0,0,0);

    cur = (cur==2) ? 0 : cur+1;
  }

  if (p == 2){
    #pragma unroll
    for (int fc=0;fc<4;fc++){
      int n = n0 + wc*64 + fc*16 + lr;
      float bias = Bb[n];
      int h = n>>6, d = n&63;
      #pragma unroll
      for (int fr=0;fr<4;fr++){
        int m = m0 + wr*64 + fr*16 + lg*4;
        int b = m>>11, s = m & 2047;
        uint2 u;
        u.x = cvt_pk_bf16(acc[fr][fc][0]+bias, acc[fr][fc][1]+bias);
        u.y = cvt_pk_bf16(acc[fr][fc][2]+bias, acc[fr][fc][3]+bias);
        *(uint2*)(Out + (((size_t)((b<<4)+h)*64 + d)*2048 + s)) = u;
      }
    }
  } else {
    #pragma unroll
    for (int fc=0;fc<4;fc++){
      int n = n0 + wc*64 + fc*16 + lr;
      float bias = Bb[n];
      int h = n>>6, d = n&63;
      #pragma unroll
      for (int fr=0;fr<4;fr++){
        #pragma unroll
        for (int r=0;r<4;r++){
          int m = m0 + wr*64 + fr*16 + lg*4 + r;
          int b = m>>11, s = m & 2047;
          float v = (acc[fr][fc][r] + bias) * oscale;
          Out[ ((size_t)((b<<4)+h)*2048 + (size_t)s)*64 + d ] = f2bf(v);
        }
      }
    }
  }
}

// ---------------------------------------------------------------------------
// Kernel 2: causal flash attention — paired q-tiles, 2 waves/SIMD, and now
// COUNTED staging: per macro-step, order is vmcnt(0)-wait (only AGED loads
// outstanding) -> raw s_barrier -> issue stage(mj+1) -> compute(mj).
// The old per-step __syncthreads drained the freshly-issued next-tile loads
// (vmcnt(0) before s_barrier semantics) — now compute covers them.
// 2-buffer safety: barrier at step mj proves compute(mj-1) done in all waves.
// ---------------------------------------------------------------------------
__global__ __launch_bounds__(256, 2) void attn_kernel(
  const unsigned short* __restrict__ Q, const unsigned short* __restrict__ Kg,
  const unsigned short* __restrict__ Vt, unsigned short* __restrict__ AO)
{
  const int idx = blockIdx.x;
  const int xcd = idx & 7, j0 = idx >> 3;
  const int bh = 4*xcd + (j0 & 3);
  const int pr = j0 >> 2;                 // pair index 0..15
  const size_t base = (size_t)bh * 131072; // 2048*64
  const int tid = threadIdx.x, w = tid>>6, l = tid&63;
  const int lq = l & 31, hi = l >> 5;
  const int qhalf = w >> 1, par = w & 1;
  const int b = bh>>4, hh = bh&15;

  __shared__ unsigned short Ks[2][8192];   // [128 kv][64 d], row-swizzled
  __shared__ unsigned short Vs[2][8192];   // [64 d][128 kv], row-swizzled

  auto stage = [&](int mj, int half){
    const int kv0 = mj*128;
    #pragma unroll
    for (int i=0;i<4;i++){
      int c = tid + i*256;
      int krow = c>>3;
      int kc = (c&7) ^ (krow&7);
      gload_lds16(Kg + base + (size_t)(kv0+krow)*64 + kc*8, &Ks[half][0] + c*8);
      int vrow = c>>4;
      int vc = (c&15) ^ (vrow&15);
      gload_lds16(Vt + base + (size_t)vrow*2048 + kv0 + vc*8, &Vs[half][0] + c*8);
    }
  };

  #pragma unroll 1
  for (int ph=0; ph<2; ph++){
    const int t = ph ? pr : (31 - pr);    // heavy tile first
    const int q0 = t*64;
    const int qw0 = q0 + qhalf*32;
    const int qq = qw0 + lq;
    const int NT = t + 1;                 // 64-kv tiles
    const int M = (NT+1) >> 1;            // 128-kv macro-steps

    bf16x8 qf[4];
    {
      const unsigned short* qp = Q + base + (size_t)qq*64;
      #pragma unroll
      for (int s=0;s<4;s++) qf[s] = *(const bf16x8*)(qp + s*16 + hi*8);
    }

    f32x16 oacc[2];
    #pragma unroll
    for (int dt=0;dt<2;dt++)
      #pragma unroll
      for (int r=0;r<16;r++) oacc[dt][r] = 0.f;
    float m_i = -INFINITY, l_i = 0.f;

    __syncthreads();          // guard LDS reuse (prev phase epilogue/merge)
    stage(0, 0);

    for (int mj=0; mj<M; mj++){
      const int cur = mj & 1;
      // wait for buf[cur]'s loads (the only outstanding ones), then barrier
      asm volatile("s_waitcnt vmcnt(0)" ::: "memory");
      __builtin_amdgcn_s_barrier();
      __builtin_amdgcn_sched_barrier(0);
      // issue next macro-tile; compute below covers its L2 latency
      if (mj+1 < M) stage(mj+1, cur^1);

      const int kt = 2*mj + par;
      if (kt < NT){
        const int kv0 = kt*64;
        const int rbase = par*64;       // this wave's 64-kv half in LDS

        f32x16 sacc[2];
        #pragma unroll
        for (int kvt=0;kvt<2;kvt++)
          #pragma unroll
          for (int r=0;r<16;r++) sacc[kvt][r] = 0.f;

        __builtin_amdgcn_s_setprio(1);
        #pragma unroll
        for (int kvt=0;kvt<2;kvt++){
          int row = rbase + kvt*32 + lq;
          const char* kb = (const char*)&Ks[cur][0] + row*128;
          int swz = (row&7)<<4;
          #pragma unroll
          for (int s=0;s<4;s++){
            bf16x8 kf = *(const bf16x8*)(kb + ((s*32 + hi*16) ^ swz));
            sacc[kvt] = __builtin_amdgcn_mfma_f32_32x32x16_bf16(kf, qf[s], sacc[kvt], 0,0,0);
          }
        }
        __builtin_amdgcn_s_setprio(0);

        #pragma unroll
        for (int kvt=0;kvt<2;kvt++){
          if (kv0 + kvt*32 + 31 > qw0){
            #pragma unroll
            for (int r=0;r<16;r++){
              int kvv = kv0 + kvt*32 + (r&3) + 8*(r>>2) + 4*hi;
              if (kvv > qq) sacc[kvt][r] = -1e30f;
            }
          }
        }

        float mt = sacc[0][0];
        #pragma unroll
        for (int kvt=0;kvt<2;kvt++)
          #pragma unroll
          for (int r=0;r<16;r++) mt = fmaxf(mt, sacc[kvt][r]);
        mt = fmaxf(mt, __shfl_xor(mt, 32));

        if (__any(mt > m_i + 8.f)){
          float mn = fmaxf(m_i, mt);
          float sc = EXP2(m_i - mn);
          m_i = mn;
          l_i *= sc;
          #pragma unroll
          for (int dt=0;dt<2;dt++)
            #pragma unroll
            for (int r=0;r<16;r++) oacc[dt][r] *= sc;
        }
        float rs = 0.f;
        #pragma unroll
        for (int kvt=0;kvt<2;kvt++)
          #pragma unroll
          for (int r=0;r<16;r++){
            float pv = EXP2(sacc[kvt][r] - m_i);
            sacc[kvt][r] = pv;
            rs += pv;
          }
        rs += __shfl_xor(rs, 32);
        l_i += rs;

        unsigned pa[8], pb[8], sa[8], sb[8];
        #pragma unroll
        for (int g=0; g<8; g++){
          int kvt = g>>2, gl = g&3;
          pa[g] = cvt_pk_bf16(sacc[kvt][4*gl+0], sacc[kvt][4*gl+1]);
          pb[g] = cvt_pk_bf16(sacc[kvt][4*gl+2], sacc[kvt][4*gl+3]);
          sa[g] = __shfl_xor(pa[g], 32);
          sb[g] = __shfl_xor(pb[g], 32);
        }
        bf16x8 pfrag[4];
        #pragma unroll
        for (int s=0;s<4;s++){
          int g0 = (s>>1)*4 + 2*(s&1);
          unsigned w0 = hi ? sa[g0+1] : pa[g0];
          unsigned w1 = hi ? sb[g0+1] : pb[g0];
          unsigned w2 = hi ? pa[g0+1] : sa[g0];
          unsigned w3 = hi ? pb[g0+1] : sb[g0];
          pfrag[s] = mk8(w0, w1, w2, w3);
        }

        __builtin_amdgcn_s_setprio(1);
        #pragma unroll
        for (int dt=0;dt<2;dt++){
          int d = dt*32 + lq;
          const char* vb = (const char*)&Vs[cur][0] + d*256;
          int swz = (d&15)<<4;
          #pragma unroll
          for (int s=0;s<4;s++){
            bf16x8 vf = *(const bf16x8*)(vb + ((par*128 + s*32 + hi*16) ^ swz));
            oacc[dt] = __builtin_amdgcn_mfma_f32_32x32x16_bf16(vf, pfrag[s], oacc[dt], 0,0,0);
          }
        }
        __builtin_amdgcn_s_setprio(0);
      }
    }
    __syncthreads();           // drain everything before LDS merge reuse

    // ---- split-softmax merge: par1 partials -> LDS -> par0 combines
    float* mb = (float*)&Ks[0][0] + qhalf*2176;   // 34 regs x 64 lanes
    if (par == 1){
      #pragma unroll
      for (int dt=0;dt<2;dt++)
        #pragma unroll
        for (int r=0;r<16;r++) mb[(dt*16+r)*64 + l] = oacc[dt][r];
      mb[32*64 + l] = m_i;
      mb[33*64 + l] = l_i;
    }
    __syncthreads();
    if (par == 0){
      float m1  = mb[32*64 + l];
      float l1v = mb[33*64 + l];
      float mn = fmaxf(m_i, m1);
      float s0 = EXP2(m_i - mn);
      float s1 = EXP2(m1 - mn);
      float inv = 1.0f / (l_i*s0 + l1v*s1);
      float f0 = s0*inv, f1 = s1*inv;

      unsigned short* Es = &Vs[0][0] + qhalf*2048;
      char* eb = (char*)Es + lq*128;
      int swz = (lq&7)<<4;
      #pragma unroll
      for (int dt=0;dt<2;dt++)
        #pragma unroll
        for (int g=0;g<4;g++){
          int d0 = dt*32 + 8*g + 4*hi;
          float v0 = oacc[dt][4*g+0]*f0 + mb[(dt*16+4*g+0)*64+l]*f1;
          float v1 = oacc[dt][4*g+1]*f0 + mb[(dt*16+4*g+1)*64+l]*f1;
          float v2 = oacc[dt][4*g+2]*f0 + mb[(dt*16+4*g+2)*64+l]*f1;
          float v3 = oacc[dt][4*g+3]*f0 + mb[(dt*16+4*g+3)*64+l]*f1;
          *(unsigned*)(eb + ((d0*2    ) ^ swz)) = cvt_pk_bf16(v0, v1);
          *(unsigned*)(eb + ((d0*2 + 4) ^ swz)) = cvt_pk_bf16(v2, v3);
        }
      // same-wave readback -> coalesced stores
      const char* rb = (const char*)Es + lq*128;
      unsigned short* op = AO + ((size_t)b*2048 + qq)*1024 + hh*64 + hi*32;
      #pragma unroll
      for (int jj=0;jj<4;jj++){
        bf16x8 v = *(const bf16x8*)(rb + ((hi*64 + jj*16) ^ swz));
        *(bf16x8*)(op + jj*8) = v;
      }
    }
  }
}

// ---------------------------------------------------------------------------
// Kernel 3: output projection — NOW 64x128 tiles, 512 blocks (2/CU),
// same 3-buffer depth-2 counted-vmcnt structure (3 loads/step -> vmcnt(3)).
// ---------------------------------------------------------------------------
__global__ __launch_bounds__(256, 3) void proj_out_kernel(
  const unsigned short* __restrict__ A, const unsigned short* __restrict__ B,
  const float* __restrict__ Bb, float* __restrict__ Out)
{
  const int L = blockIdx.x;             // 512 blocks
  const int xcd = L & 7, g = L >> 3;    // g 0..63
  const int tm = xcd*8 + (g>>3);        // 0..63 (64-row panels)
  const int tn = g & 7;
  const int m0 = tm*64, n0 = tn*128;
  const int tid = threadIdx.x;
  const int w = tid>>6, l = tid&63;
  const int wr = w>>1, wc = w&1;        // wr: 32-row half, wc: 64-col half
  const int lg = l>>4, lr = l&15;

  __shared__ unsigned short As[3][2048];   // [64][32] bf16
  __shared__ unsigned short Bs[3][4096];   // [128][32] bf16

  f32x4 acc[2][4];
  #pragma unroll
  for (int i=0;i<2;i++)
    #pragma unroll
    for (int j=0;j<4;j++){ f32x4 z = {0.f,0.f,0.f,0.f}; acc[i][j] = z; }

  const int lrow = l>>2;                 // 0..15 within a wave's 16-row strip
  const int lchk = (l&3) ^ (lrow&3);     // source chunk, XOR row&3
  auto stage = [&](int h, int buf){
    const int kt = h*32;
    // A: 64 rows; wave w covers rows [w*16, w*16+16)
    gload_lds16(A + (size_t)(m0 + w*16 + lrow)*1024 + kt + lchk*8,
                &As[buf][0] + (w*16)*32);
    // B: 128 rows; wave w covers rows [j*64 + w*16, ...) for j=0,1
    #pragma unroll
    for (int jb=0;jb<2;jb++){
      int rbase = jb*64 + w*16;
      gload_lds16(B + (size_t)(n0 + rbase + lrow)*1024 + kt + lchk*8,
                  &Bs[buf][0] + rbase*32);
    }
  };

  stage(0, 0);
  stage(1, 1);

  const int sca = (lg ^ (lr&3)) << 4;
  int cur = 0;
  for (int h=0; h<32; ++h){
    if (h < 31) asm volatile("s_waitcnt vmcnt(3)" ::: "memory");
    else        asm volatile("s_waitcnt vmcnt(0)" ::: "memory");
    __builtin_amdgcn_s_barrier();
    __builtin_amdgcn_sched_barrier(0);
    if (h < 30){
      int nb = cur + 2; if (nb >= 3) nb -= 3;
      stage(h+2, nb);
    }

    bf16x8 af[2], bfr[4];
    #pragma unroll
    for (int f=0;f<2;f++)
      af[f]  = *(const bf16x8*)((const char*)&As[cur][0] + (wr*32 + f*16 + lr)*64 + sca);
    #pragma unroll
    for (int f=0;f<4;f++)
      bfr[f] = *(const bf16x8*)((const char*)&Bs[cur][0] + (wc*64 + f*16 + lr)*64 + sca);
    #pragma unroll
    for (int fr=0;fr<2;fr++)
      #pragma unroll
      for (int fc=0;fc<4;fc++)
        acc[fr][fc] = __builtin_amdgcn_mfma_f32_16x16x32_bf16(af[fr], bfr[fc], acc[fr][fc], 0,0,0);

    cur = (cur==2) ? 0 : cur+1;
  }

  #pragma unroll
  for (int fc=0;fc<4;fc++){
    int n = n0 + wc*64 + fc*16 + lr;
    float bias = Bb[n];
    #pragma unroll
    for (int fr=0;fr<2;fr++){
      #pragma unroll
      for (int r=0;r<4;r++){
        int m = m0 + wr*32 + fr*16 + lg*4 + r;
        Out[(size_t)m*1024 + n] = acc[fr][fc][r] + bias;
      }
    }
  }
}

// ---------------------------------------------------------------------------
extern "C" void kernel_launch(void* const* d_in, const int* in_sizes, int n_in,
                              void* d_out, int out_size, void* d_ws, size_t ws_size,
                              hipStream_t stream)
{
  const float* Xq = (const float*)d_in[0];
  const float* Xk = (const float*)d_in[1];
  const float* Xv = (const float*)d_in[2];
  // d_in[3] = mask (causal, static) — unused
  const float* Wq = (const float*)d_in[4];
  const float* bq = (const float*)d_in[5];
  const float* Wk = (const float*)d_in[6];
  const float* bk = (const float*)d_in[7];
  const float* Wv = (const float*)d_in[8];
  const float* bv = (const float*)d_in[9];
  const float* Wo = (const float*)d_in[10];
  const float* bo = (const float*)d_in[11];

  unsigned short* ws  = (unsigned short*)d_ws;
  unsigned short* Xb  = ws;
  unsigned short* Wb  = ws + 12582912;
  unsigned short* Qw  = ws + 16777216;
  unsigned short* Kw  = ws + 20971520;
  unsigned short* Vw  = ws + 25165824;
  unsigned short* AOw = ws + 29360128;
  float* out = (float*)d_out;

  convert_kernel<<<dim3(512,7), 256, 0, stream>>>(Xq,Xk,Xv,Wq,Wk,Wv,Wo, ws);
  proj_qkv_kernel<<<768, 256, 0, stream>>>(Xb, Wb, bq,bk,bv, Qw,Kw,Vw);
  attn_kernel<<<512, 256, 0, stream>>>(Qw,Kw,Vw,AOw);
  proj_out_kernel<<<512, 256, 0, stream>>>(AOw, Wb + 3*1048576, bo, out);
}